// Round 5
// baseline (250.873 us; speedup 1.0000x reference)
//
#include <hip/hip_runtime.h>
#include <math.h>

#define BATCH 4096
#define SEQ_T 512
#define ISZ   4
#define HID   64
#define OSZ   40
#define RPB   16     // batch rows per block (MFMA N); grid = 256 = 1 block/CU

typedef __attribute__((ext_vector_type(8))) _Float16     half8;
typedef __attribute__((ext_vector_type(2))) _Float16     half2v;
typedef __attribute__((ext_vector_type(4))) float        float4v;
typedef __attribute__((ext_vector_type(2))) unsigned int uint2v;

static __device__ __forceinline__ half2v pk_f16(float a, float b) {
    return __builtin_bit_cast(half2v, __builtin_amdgcn_cvt_pkrtz(a, b)); // v_cvt_pkrtz_f16_f32
}

// Rational tanh (Eigen/XNNPACK 13/6 Padé): clamp -> x^2 -> Estrin num || Horner
// den -> rcp -> mul. ~1e-6 abs error; one trans op (rcp) instead of exp+rcp,
// and the FMA tree is shorter than the dependent exp->add->rcp chain (r4
// post-mortem: trans dep-latency is a big chain term).
static __device__ __forceinline__ float fast_tanh(float x) {
    const float c = 7.90531110763549805f;
    x = fminf(fmaxf(x, -c), c);
    float t  = x * x;
    float t2 = t * t;
    float hi  = fmaf(t, -2.76076847742355e-16f, 2.00018790482477e-13f); // a13 t + a11
    hi        = fmaf(t, hi, -8.60467152213735e-11f);                    // + a9
    float mid = fmaf(t, 5.12229709037114e-08f, 1.48572235717979e-05f);  // a7 t + a5
    float lo  = fmaf(t, 6.37261928875436e-04f, 4.89352455891786e-03f);  // a3 t + a1
    float np  = fmaf(t2, hi, mid);
    np        = fmaf(t2, np, lo);
    float num = x * np;
    float dp  = fmaf(t, 1.19825839466702e-06f, 1.18534705686654e-04f);
    dp        = fmaf(t, dp, 2.26843463243900e-03f);
    dp        = fmaf(t, dp, 4.89352518554385e-03f);
    return num * __builtin_amdgcn_rcpf(dp);
}

// LDS-only barrier: ds_writes drained (lgkmcnt), global x prefetches stay in flight.
#define LDS_BARRIER() asm volatile("s_waitcnt lgkmcnt(0)\n\ts_barrier" ::: "memory")

// Phase-split schedule (r4: confirmed, 740cy/update all-chain): group 0 computes
// even updates, group 1 odd updates; dependent chains tile the timeline, issue
// hides in the shadow phase. r5: chain shortened — 6 INDEPENDENT MFMA
// accumulators (depth 1 + add tree) instead of two 3-deep chains; rational
// tanh; setprio(1) on the active wave.
__global__ __launch_bounds__(512, 1)
void rnn_f16x2_kernel(const float* __restrict__ x,
                      const float* __restrict__ W_ih,
                      const float* __restrict__ W_hh,
                      const float* __restrict__ b_ih,
                      const float* __restrict__ b_hh,
                      const float* __restrict__ fc_W,
                      const float* __restrict__ fc_b,
                      float* __restrict__ out)
{
    // hterm[buf][tau][g][n][j] = h_tau[k=8g+j] for batch col n (B-fragment-native).
    // Reader lane(n,q): b128 at [tau][4c+q][n][0] -> 2-way bank alias (free).
    // Writer lane(n,q) wave wg: rows 16wg+4q+r -> g=2wg+(q>>1), j0=4(q&1): b64, 2-way.
    __shared__ __attribute__((aligned(16))) _Float16 hterm[2][2][8][16][8];
    __shared__ __attribute__((aligned(16))) float hf[16][68];

    const int tid  = threadIdx.x;
    const int grp  = tid >> 8;         // 0: even updates, 1: odd updates
    const int wg   = (tid >> 6) & 3;   // wave-in-group: M-slice of H
    const int lane = tid & 63;
    const int n    = lane & 15;        // A: row m; B/C/D: batch col n
    const int q    = lane >> 4;
    const int blk0 = blockIdx.x * RPB;

    // h(0) = 0: zero both buffers
    {
        unsigned int* p = (unsigned int*)hterm;
        #pragma unroll
        for (int i = tid; i < (int)(sizeof(hterm) / 4); i += 512) p[i] = 0u;
    }

    // ---- static A fragments: W_hh row 16wg+n, 2-term fp16 split, K-chunks c=0,1 ----
    half8 A10, A11, A20, A21;   // A1x = hi term, A2x = residual term
    {
        const float* wr = W_hh + (16 * wg + n) * HID;
        #pragma unroll
        for (int j = 0; j < 8; ++j) {
            float f0 = wr[     8 * q + j];
            float f1 = wr[32 + 8 * q + j];
            _Float16 h0 = (_Float16)f0; A10[j] = h0; A20[j] = (_Float16)(f0 - (float)h0);
            _Float16 h1 = (_Float16)f1; A11[j] = h1; A21[j] = (_Float16)(f1 - (float)h1);
        }
    }

    // ---- fp32 x-projection weights + bias for C rows 16wg + 4q + r ----
    const int r0 = 16 * wg + 4 * q;
    float wih[4][4], bias[4];
    #pragma unroll
    for (int r = 0; r < 4; ++r) {
        bias[r] = b_ih[r0 + r] + b_hh[r0 + r];
        #pragma unroll
        for (int i = 0; i < ISZ; ++i) wih[r][i] = W_ih[(r0 + r) * ISZ + i];
    }

    // ---- per-group x pipeline: this group's updates are u = grp, grp+2, ... ----
    const float* xrow = x + (size_t)(blk0 + n) * SEQ_T * ISZ;
    float4v x1 = *(const float4v*)(xrow + (size_t)(grp    ) * ISZ);
    float4v x2 = *(const float4v*)(xrow + (size_t)(grp + 2) * ISZ);
    float4v x3 = *(const float4v*)(xrow + (size_t)(grp + 4) * ISZ);
    int tnext = grp + 6;

    const int gw = 2 * wg + (q >> 1);
    const int j0 = 4 * (q & 1);

    float p0, p1, p2, p3;
    float hl0 = 0.f, hl1 = 0.f, hl2 = 0.f, hl3 = 0.f;

    __syncthreads();   // zero-init visible (prologue: full drain fine)

#define MFMA16(A, B, C) __builtin_amdgcn_mfma_f32_16x16x32_f16((A), (B), (C), 0, 0, 0)

#define XP_COMPUTE()                                                           \
    {                                                                          \
        p0 = bias[0]; p1 = bias[1]; p2 = bias[2]; p3 = bias[3];                \
        _Pragma("unroll")                                                      \
        for (int i = 0; i < ISZ; ++i) {                                        \
            p0 = fmaf(x1[i], wih[0][i], p0);                                   \
            p1 = fmaf(x1[i], wih[1][i], p1);                                   \
            p2 = fmaf(x1[i], wih[2][i], p2);                                   \
            p3 = fmaf(x1[i], wih[3][i], p3);                                   \
        }                                                                      \
    }

#define XSHIFT()                                                               \
    {                                                                          \
        int tn = tnext; if (tn > SEQ_T - 1) tn = SEQ_T - 1;                    \
        float4v xf = *(const float4v*)(xrow + (size_t)tn * ISZ);               \
        tnext += 2;                                                            \
        x1 = x2; x2 = x3; x3 = xf;                                             \
    }

// 6 independent MFMAs (xp rides as C of the first), f32 add tree depth 2.
// Chain = 1 MFMA dep-latency + ~24cy adds, vs r4's 3 MFMA dep-latencies.
#define ACTIVE_STEP(RB, WB)                                                    \
    {                                                                          \
        __builtin_amdgcn_s_setprio(1);                                         \
        half8 B10 = *(const half8*)&hterm[RB][0][    q][n][0];                 \
        half8 B11 = *(const half8*)&hterm[RB][0][4 + q][n][0];                 \
        half8 B20 = *(const half8*)&hterm[RB][1][    q][n][0];                 \
        half8 B21 = *(const half8*)&hterm[RB][1][4 + q][n][0];                 \
        const float4v zz = {0.f, 0.f, 0.f, 0.f};                               \
        float4v c1 = {p0, p1, p2, p3};                                         \
        float4v a1 = MFMA16(A10, B10, c1);                                     \
        float4v a2 = MFMA16(A11, B11, zz);                                     \
        float4v a3 = MFMA16(A10, B20, zz);                                     \
        float4v a4 = MFMA16(A11, B21, zz);                                     \
        float4v a5 = MFMA16(A20, B10, zz);                                     \
        float4v a6 = MFMA16(A21, B11, zz);                                     \
        float4v s12 = a1 + a2, s34 = a3 + a4, s56 = a5 + a6;                   \
        float4v sal = (s12 + s34) + s56;                                       \
        hl0 = fast_tanh(sal[0]); hl1 = fast_tanh(sal[1]);                      \
        hl2 = fast_tanh(sal[2]); hl3 = fast_tanh(sal[3]);                      \
        half2v hi01 = pk_f16(hl0, hl1), hi23 = pk_f16(hl2, hl3);               \
        float s0 = hl0 - (float)hi01[0], s1 = hl1 - (float)hi01[1];            \
        float s2 = hl2 - (float)hi23[0], s3 = hl3 - (float)hi23[1];            \
        half2v lo01 = pk_f16(s0, s1), lo23 = pk_f16(s2, s3);                   \
        uint2v whi = { __builtin_bit_cast(unsigned int, hi01),                 \
                       __builtin_bit_cast(unsigned int, hi23) };               \
        uint2v wlo = { __builtin_bit_cast(unsigned int, lo01),                 \
                       __builtin_bit_cast(unsigned int, lo23) };               \
        *(uint2v*)&hterm[WB][0][gw][n][j0] = whi;                              \
        *(uint2v*)&hterm[WB][1][gw][n][j0] = wlo;                              \
        __builtin_amdgcn_s_setprio(0);                                         \
    }

    if (grp == 0) {
        // even updates: active in phase A, xp-precompute in phase B (idle)
        XP_COMPUTE(); XSHIFT();                  // xp for update 0
        for (int it = 0; it < SEQ_T / 2; ++it) {
            ACTIVE_STEP(0, 1);                   // update 2*it: buf0 -> buf1
            LDS_BARRIER();
            XP_COMPUTE(); XSHIFT();              // xp for update 2*it+2
            LDS_BARRIER();
        }
    } else {
        // odd updates: xp-precompute in phase A (idle), active in phase B
        for (int it = 0; it < SEQ_T / 2; ++it) {
            XP_COMPUTE(); XSHIFT();              // xp for update 2*it+1
            LDS_BARRIER();
            ACTIVE_STEP(1, 0);                   // update 2*it+1: buf1 -> buf0
            LDS_BARRIER();
        }
    }
#undef ACTIVE_STEP
#undef XSHIFT
#undef XP_COMPUTE
#undef MFMA16

    // ---- fc epilogue: final h (update 511) lives in group 1's registers ----
    if (grp == 1) {
        float4v hv = {hl0, hl1, hl2, hl3};
        *(float4v*)&hf[n][r0] = hv;
    }
    __syncthreads();
    for (int it = tid; it < RPB * OSZ; it += 512) {
        const int b = it / OSZ;
        const int o = it - b * OSZ;
        const float* wo = fc_W + o * HID;
        float acc = fc_b[o];
        #pragma unroll
        for (int j = 0; j < HID; ++j)
            acc = fmaf(hf[b][j], wo[j], acc);
        out[(size_t)(blk0 + b) * OSZ + o] = acc;
    }
}

extern "C" void kernel_launch(void* const* d_in, const int* in_sizes, int n_in,
                              void* d_out, int out_size, void* d_ws, size_t ws_size,
                              hipStream_t stream) {
    const float* x    = (const float*)d_in[0];
    const float* W_ih = (const float*)d_in[1];
    const float* W_hh = (const float*)d_in[2];
    const float* b_ih = (const float*)d_in[3];
    const float* b_hh = (const float*)d_in[4];
    const float* fc_W = (const float*)d_in[5];
    const float* fc_b = (const float*)d_in[6];
    float* out = (float*)d_out;

    rnn_f16x2_kernel<<<BATCH / RPB, 512, 0, stream>>>(
        x, W_ih, W_hh, b_ih, b_hh, fc_W, fc_b, out);
}

// Round 6
// 214.018 us; speedup vs baseline: 1.1722x; 1.1722x over previous
//
#include <hip/hip_runtime.h>
#include <math.h>

#define BATCH 4096
#define SEQ_T 512
#define ISZ   4
#define HID   64
#define OSZ   40
#define RPB   16     // batch rows per block (MFMA N); grid = 256 = 1 block/CU

typedef __attribute__((ext_vector_type(8))) _Float16     half8;
typedef __attribute__((ext_vector_type(2))) _Float16     half2v;
typedef __attribute__((ext_vector_type(4))) float        float4v;
typedef __attribute__((ext_vector_type(2))) unsigned int uint2v;

static __device__ __forceinline__ half2v pk_f16(float a, float b) {
    return __builtin_bit_cast(half2v, __builtin_amdgcn_cvt_pkrtz(a, b)); // v_cvt_pkrtz_f16_f32
}

// tanh(x) = 1 - 2/(exp2(x*2*log2e)+1); saturating, NaN-free (r4 form — r5's
// rational variant added chain FMAs and doubled absmax; reverted)
static __device__ __forceinline__ float fast_tanh(float x) {
    float e = __builtin_amdgcn_exp2f(x * 2.885390081777927f);
    return fmaf(-2.0f, __builtin_amdgcn_rcpf(e + 1.0f), 1.0f);
}

// LDS-only barrier: ds_writes drained (lgkmcnt), global x prefetches stay in flight.
#define LDS_BARRIER() asm volatile("s_waitcnt lgkmcnt(0)\n\ts_barrier" ::: "memory")

// Phase-split schedule (r4, 158us): group 0 even updates, group 1 odd updates;
// dependent chains tile the timeline. r6 single change: the XP phase's register
// pipeline x1=x2;x2=x3;x3=xf forced a vmcnt wait on a load issued ~10 instrs
// earlier -> exposed ~200-900cy x-load latency in every shadow phase, which is
// on the critical path via barrier arrival (r5 post-mortem: this is r4's
// missing ~260cy/update). Fix: 4 named regs, loop unrolled x4, each phase
// consumes one reg then reloads IT in place. No moves touch an in-flight load;
// load->first-use distance = 4 phase-pairs (~1200cy) > worst-case HBM (~900cy).
__global__ __launch_bounds__(512, 1)
void rnn_f16x2_kernel(const float* __restrict__ x,
                      const float* __restrict__ W_ih,
                      const float* __restrict__ W_hh,
                      const float* __restrict__ b_ih,
                      const float* __restrict__ b_hh,
                      const float* __restrict__ fc_W,
                      const float* __restrict__ fc_b,
                      float* __restrict__ out)
{
    // hterm[buf][tau][g][n][j] = h_tau[k=8g+j] for batch col n (B-fragment-native).
    // Reader lane(n,q): b128 at [tau][4c+q][n][0] -> 2-way bank alias (free).
    // Writer lane(n,q) wave wg: rows 16wg+4q+r -> g=2wg+(q>>1), j0=4(q&1): b64, 2-way.
    __shared__ __attribute__((aligned(16))) _Float16 hterm[2][2][8][16][8];
    __shared__ __attribute__((aligned(16))) float hf[16][68];

    const int tid  = threadIdx.x;
    const int grp  = tid >> 8;         // 0: even updates, 1: odd updates
    const int wg   = (tid >> 6) & 3;   // wave-in-group: M-slice of H
    const int lane = tid & 63;
    const int n    = lane & 15;        // A: row m; B/C/D: batch col n
    const int q    = lane >> 4;
    const int blk0 = blockIdx.x * RPB;

    // h(0) = 0: zero both buffers
    {
        unsigned int* p = (unsigned int*)hterm;
        #pragma unroll
        for (int i = tid; i < (int)(sizeof(hterm) / 4); i += 512) p[i] = 0u;
    }

    // ---- static A fragments: W_hh row 16wg+n, 2-term fp16 split, K-chunks c=0,1 ----
    half8 A10, A11, A20, A21;   // A1x = hi term, A2x = residual term
    {
        const float* wr = W_hh + (16 * wg + n) * HID;
        #pragma unroll
        for (int j = 0; j < 8; ++j) {
            float f0 = wr[     8 * q + j];
            float f1 = wr[32 + 8 * q + j];
            _Float16 h0 = (_Float16)f0; A10[j] = h0; A20[j] = (_Float16)(f0 - (float)h0);
            _Float16 h1 = (_Float16)f1; A11[j] = h1; A21[j] = (_Float16)(f1 - (float)h1);
        }
    }

    // ---- fp32 x-projection weights + bias for C rows 16wg + 4q + r ----
    const int r0 = 16 * wg + 4 * q;
    float wih[4][4], bias[4];
    #pragma unroll
    for (int r = 0; r < 4; ++r) {
        bias[r] = b_ih[r0 + r] + b_hh[r0 + r];
        #pragma unroll
        for (int i = 0; i < ISZ; ++i) wih[r][i] = W_ih[(r0 + r) * ISZ + i];
    }

    // ---- 4-deep named x pipeline: this group's updates are u = grp, grp+2, ... ----
    const float* xrow = x + (size_t)(blk0 + n) * SEQ_T * ISZ;
    float4v xa = *(const float4v*)(xrow + (size_t)(grp    ) * ISZ);
    float4v xb = *(const float4v*)(xrow + (size_t)(grp + 2) * ISZ);
    float4v xc = *(const float4v*)(xrow + (size_t)(grp + 4) * ISZ);
    float4v xd = *(const float4v*)(xrow + (size_t)(grp + 6) * ISZ);
    int tnext = grp + 8;

    const int gw = 2 * wg + (q >> 1);
    const int j0 = 4 * (q & 1);

    float p0, p1, p2, p3;
    float hl0 = 0.f, hl1 = 0.f, hl2 = 0.f, hl3 = 0.f;

    __syncthreads();   // zero-init visible (prologue: full drain fine)

#define MFMA16(A, B, C) __builtin_amdgcn_mfma_f32_16x16x32_f16((A), (B), (C), 0, 0, 0)

// Consume XR (xp projection), then reload the SAME register in place for use
// 4 phase-pairs later. Consumption reads, then the load overwrites; the next
// read of XR (4 iterations on) carries the vmcnt wait — fully covered.
#define XP_FROM(XR)                                                            \
    {                                                                          \
        p0 = bias[0]; p1 = bias[1]; p2 = bias[2]; p3 = bias[3];                \
        _Pragma("unroll")                                                      \
        for (int i = 0; i < ISZ; ++i) {                                        \
            p0 = fmaf(XR[i], wih[0][i], p0);                                   \
            p1 = fmaf(XR[i], wih[1][i], p1);                                   \
            p2 = fmaf(XR[i], wih[2][i], p2);                                   \
            p3 = fmaf(XR[i], wih[3][i], p3);                                   \
        }                                                                      \
    }

#define XRELOAD(XR)                                                            \
    {                                                                          \
        int tn = tnext; if (tn > SEQ_T - 1) tn = SEQ_T - 1;                    \
        XR = *(const float4v*)(xrow + (size_t)tn * ISZ);                       \
        tnext += 2;                                                            \
    }

// r4 form: two 3-deep C-chained accumulator chains (C read late in the MFMA
// pipe -> chained accumulation issues near back-to-back; r5's de-chaining +
// add tree was a regression).
#define ACTIVE_STEP(RB, WB)                                                    \
    {                                                                          \
        half8 B10 = *(const half8*)&hterm[RB][0][    q][n][0];                 \
        half8 B11 = *(const half8*)&hterm[RB][0][4 + q][n][0];                 \
        half8 B20 = *(const half8*)&hterm[RB][1][    q][n][0];                 \
        half8 B21 = *(const half8*)&hterm[RB][1][4 + q][n][0];                 \
        float4v accA = {p0, p1, p2, p3};                                       \
        float4v accB = {0.f, 0.f, 0.f, 0.f};                                   \
        accA = MFMA16(A10, B10, accA);  accB = MFMA16(A11, B11, accB);         \
        accA = MFMA16(A10, B20, accA);  accB = MFMA16(A11, B21, accB);         \
        accA = MFMA16(A20, B10, accA);  accB = MFMA16(A21, B11, accB);         \
        hl0 = fast_tanh(accA[0] + accB[0]); hl1 = fast_tanh(accA[1] + accB[1]);\
        hl2 = fast_tanh(accA[2] + accB[2]); hl3 = fast_tanh(accA[3] + accB[3]);\
        half2v hi01 = pk_f16(hl0, hl1), hi23 = pk_f16(hl2, hl3);               \
        float s0 = hl0 - (float)hi01[0], s1 = hl1 - (float)hi01[1];            \
        float s2 = hl2 - (float)hi23[0], s3 = hl3 - (float)hi23[1];            \
        half2v lo01 = pk_f16(s0, s1), lo23 = pk_f16(s2, s3);                   \
        uint2v whi = { __builtin_bit_cast(unsigned int, hi01),                 \
                       __builtin_bit_cast(unsigned int, hi23) };               \
        uint2v wlo = { __builtin_bit_cast(unsigned int, lo01),                 \
                       __builtin_bit_cast(unsigned int, lo23) };               \
        *(uint2v*)&hterm[WB][0][gw][n][j0] = whi;                              \
        *(uint2v*)&hterm[WB][1][gw][n][j0] = wlo;                              \
    }

    if (grp == 0) {
        // even updates: active in phase A, xp-precompute in phase B (idle)
        XP_FROM(xa); XRELOAD(xa);                // xp for update 0
        for (int it = 0; it < SEQ_T / 2; it += 4) {
            ACTIVE_STEP(0, 1); LDS_BARRIER(); XP_FROM(xb); XRELOAD(xb); LDS_BARRIER();
            ACTIVE_STEP(0, 1); LDS_BARRIER(); XP_FROM(xc); XRELOAD(xc); LDS_BARRIER();
            ACTIVE_STEP(0, 1); LDS_BARRIER(); XP_FROM(xd); XRELOAD(xd); LDS_BARRIER();
            ACTIVE_STEP(0, 1); LDS_BARRIER(); XP_FROM(xa); XRELOAD(xa); LDS_BARRIER();
        }
    } else {
        // odd updates: xp-precompute in phase A (idle), active in phase B
        for (int it = 0; it < SEQ_T / 2; it += 4) {
            XP_FROM(xa); XRELOAD(xa); LDS_BARRIER(); ACTIVE_STEP(1, 0); LDS_BARRIER();
            XP_FROM(xb); XRELOAD(xb); LDS_BARRIER(); ACTIVE_STEP(1, 0); LDS_BARRIER();
            XP_FROM(xc); XRELOAD(xc); LDS_BARRIER(); ACTIVE_STEP(1, 0); LDS_BARRIER();
            XP_FROM(xd); XRELOAD(xd); LDS_BARRIER(); ACTIVE_STEP(1, 0); LDS_BARRIER();
        }
    }
#undef ACTIVE_STEP
#undef XRELOAD
#undef XP_FROM
#undef MFMA16

    // ---- fc epilogue: final h (update 511) lives in group 1's registers ----
    if (grp == 1) {
        float4v hv = {hl0, hl1, hl2, hl3};
        *(float4v*)&hf[n][r0] = hv;
    }
    __syncthreads();
    for (int it = tid; it < RPB * OSZ; it += 512) {
        const int b = it / OSZ;
        const int o = it - b * OSZ;
        const float* wo = fc_W + o * HID;
        float acc = fc_b[o];
        #pragma unroll
        for (int j = 0; j < HID; ++j)
            acc = fmaf(hf[b][j], wo[j], acc);
        out[(size_t)(blk0 + b) * OSZ + o] = acc;
    }
}

extern "C" void kernel_launch(void* const* d_in, const int* in_sizes, int n_in,
                              void* d_out, int out_size, void* d_ws, size_t ws_size,
                              hipStream_t stream) {
    const float* x    = (const float*)d_in[0];
    const float* W_ih = (const float*)d_in[1];
    const float* W_hh = (const float*)d_in[2];
    const float* b_ih = (const float*)d_in[3];
    const float* b_hh = (const float*)d_in[4];
    const float* fc_W = (const float*)d_in[5];
    const float* fc_b = (const float*)d_in[6];
    float* out = (float*)d_out;

    rnn_f16x2_kernel<<<BATCH / RPB, 512, 0, stream>>>(
        x, W_ih, W_hh, b_ih, b_hh, fc_W, fc_b, out);
}